// Round 9
// baseline (44.225 us; speedup 1.0000x reference)
//
#include <hip/hip_runtime.h>

// ---- problem constants (fixed by the reference) ----
#define BATCH   32
#define L1N     8192
#define L2N     32768
#define LTOT    40960
#define CD      32       // CONV_DEPTH
#define O1      256      // EMBED_DIM
#define L1P     1024     // L1N / 8
#define L2P     4096     // L2N / 8

typedef __attribute__((ext_vector_type(8))) _Float16 h16x8;
typedef __attribute__((ext_vector_type(4))) float f32x4;

// ---------------------------------------------------------------------------
// Fused pre-pass + scans.  grid.x = 320 blocks of 256:
//   blocks 0..31   : order1 scan (b = bid)
//   blocks 32..63  : dst2 scan + cnt2 (b = bid-32)
//   blocks 64..319 : w1h/vd1h/se1h conversion + conv2 table-x-weight products
// vd1h[(val*7+dep)] = ve1[val] + de1[dep]           (119 rows x 32 ch, fp16)
// vdw2[r][s][o] = sum_c (ve2[v]+de2[d])[c]*w2[o][c][s]   (119 x 8 x 32)
// sew2[p][s][o] = sum_c se2flat[p][c]*w2[o][c][s]        (384 x 8 x 32)
// ---------------------------------------------------------------------------
__global__ __launch_bounds__(256) void k_prescan(
        const int* __restrict__ value,
        const float* __restrict__ w1, const float* __restrict__ w2,
        const float* __restrict__ ve1, const float* __restrict__ de1,
        const float* __restrict__ se1, const float* __restrict__ ve2,
        const float* __restrict__ de2, const float* __restrict__ se2,
        _Float16* __restrict__ w1h, _Float16* __restrict__ vd1h,
        _Float16* __restrict__ se1h,
        _Float16* __restrict__ vdw2, _Float16* __restrict__ sew2,
        int* __restrict__ order1, int* __restrict__ dst2,
        int* __restrict__ cnt2) {
    int bid = blockIdx.x, tid = threadIdx.x;
    if (bid >= 64) {
        int ib = bid - 64;
        int i = ib * 256 + tid;
        if (i < 65536) {
            int o = i >> 8, k = i & 255, s = k >> 5, c = k & 31;
            w1h[i] = (_Float16)w1[o * 256 + c * 8 + s];
        }
        if (i < 3808) {                        // 119 rows x 32
            int row = i >> 5, c = i & 31;
            int v = row / 7, d = row % 7;
            vd1h[i] = (_Float16)(ve1[v * 32 + c] + de1[d * 32 + c]);
        }
        if (i < 12288) se1h[i] = (_Float16)se1[i];

        // ---- conv2 table-x-weight precompute: 2 rows per block ----
        __shared__ float w2l[32 * 257];        // padded: o*257 + (c*8+s)
        __shared__ float lrow[32];
        #pragma unroll
        for (int it = 0; it < 32; ++it) {
            int idx = it * 256 + tid;          // 8192 floats
            int o = idx >> 8, k = idx & 255;
            w2l[o * 257 + k] = w2[idx];
        }
        __syncthreads();
        for (int rr = 0; rr < 2; ++rr) {
            int r = ib * 2 + rr;
            if (r >= 503) break;
            if (tid < 32) {
                float x;
                if (r < 119) { int v = r / 7, d = r % 7;
                    x = ve2[v * 32 + tid] + de2[d * 32 + tid]; }
                else x = se2[(r - 119) * 32 + tid];
                lrow[tid] = x;
            }
            __syncthreads();
            int s = tid >> 5, o = tid & 31;
            float sum = 0.f;
            #pragma unroll
            for (int c = 0; c < 32; ++c)
                sum += lrow[c] * w2l[o * 257 + c * 8 + s];
            if (r < 119) vdw2[(r * 8 + s) * 32 + o] = (_Float16)sum;
            else sew2[((r - 119) * 8 + s) * 32 + o] = (_Float16)sum;
            __syncthreads();
        }
        return;
    }
    int lane = tid & 63, wid = tid >> 6;
    __shared__ int wsum[4];
    if (bid < 32) {
        int b = bid;
        const int4* v = (const int4*)(value + b * LTOT) + tid * 8;  // 32 ints
        int4 r[8];
        #pragma unroll
        for (int j = 0; j < 8; ++j) r[j] = v[j];
        int cnt = 0;
        #pragma unroll
        for (int j = 0; j < 8; ++j)
            cnt += (r[j].x == 2) + (r[j].y == 2) + (r[j].z == 2) + (r[j].w == 2);
        int sc = cnt;
        #pragma unroll
        for (int d = 1; d < 64; d <<= 1) {
            int t = __shfl_up(sc, d);
            if (lane >= d) sc += t;
        }
        if (lane == 63) wsum[wid] = sc;
        __syncthreads();
        int base = 0;
        for (int w = 0; w < 4; ++w) if (w < wid) base += wsum[w];
        int run = base + sc - cnt;             // exclusive prefix
        int4* o = (int4*)(order1 + b * L1N + tid * 32);
        #pragma unroll
        for (int j = 0; j < 8; ++j) {
            int vv[4] = {r[j].x, r[j].y, r[j].z, r[j].w};
            int ot[4];
            #pragma unroll
            for (int i = 0; i < 4; ++i) {
                bool m = (vv[i] == 2);
                int ord = run < (L2P - 1) ? run : (L2P - 1);
                ot[i] = m ? ord : -1;
                run += m;
            }
            o[j] = make_int4(ot[0], ot[1], ot[2], ot[3]);
        }
    } else {
        int b = bid - 32;
        const int* v2 = value + b * LTOT + L1N + tid * 16 * 8;
        int m[16]; int cnt = 0;
        #pragma unroll
        for (int i = 0; i < 16; ++i) { m[i] = (v2[i * 8] != 0); cnt += m[i]; }
        int sc = cnt;
        #pragma unroll
        for (int d = 1; d < 64; d <<= 1) {
            int t = __shfl_up(sc, d);
            if (lane >= d) sc += t;
        }
        if (lane == 63) wsum[wid] = sc;
        __syncthreads();
        int base = 0;
        for (int w = 0; w < 4; ++w) if (w < wid) base += wsum[w];
        int run = base + sc - cnt;
        int* o = dst2 + b * L2P + tid * 16;
        #pragma unroll
        for (int i = 0; i < 16; i += 4) {
            int ot[4];
            #pragma unroll
            for (int k2 = 0; k2 < 4; ++k2) { ot[k2] = m[i + k2] ? run : -1; run += m[i + k2]; }
            *(int4*)(o + i) = make_int4(ot[0], ot[1], ot[2], ot[3]);
        }
        if (tid == 255) cnt2[b] = base + sc;
    }
}

// ---------------------------------------------------------------------------
// conv2 (precomputed-product gather-sum): y[row][o] = bias[o] +
//   sum_{s=0..7} ( vdw2[rv_s][s][o] + sew2[p0_s][s][o] + sew2[p1_s][s][o]
//                + sew2[p2_s][s][o] )
// No MFMA, no GEMM LDS, no in-loop barriers.  Thread = (row, quarter-of-32).
// Block: 64 rows x 4 quarters = 256 threads; 2048 blocks.
// ---------------------------------------------------------------------------
__global__ __launch_bounds__(256, 4) void k_conv2(
    const int* __restrict__ value, const int* __restrict__ depth,
    const int* __restrict__ pos,
    const _Float16* __restrict__ vdw2, const _Float16* __restrict__ sew2,
    const float* __restrict__ b2,
    const int* __restrict__ dst2, _Float16* __restrict__ y_c) {
    int tid = threadIdx.x, q = tid & 3, rg = tid >> 2;
    int g0 = blockIdx.x * 64, b = g0 >> 12, l2b = g0 & (L2P - 1);
    __shared__ int sval[512], sdep[512], spos[1536];
    {
        int tok0 = b * LTOT + L1N + l2b * 8;
        const int4* vsrc = (const int4*)(value + tok0);
        const int4* dsrc = (const int4*)(depth + tok0);
        const int4* psrc = (const int4*)(pos + (size_t)tok0 * 3);
        if (tid < 128) ((int4*)sval)[tid] = vsrc[tid];
        else           ((int4*)sdep)[tid - 128] = dsrc[tid - 128];
        ((int4*)spos)[tid] = psrc[tid];                   // 0..255
        if (tid < 128) ((int4*)spos)[256 + tid] = psrc[256 + tid];
    }
    __syncthreads();

    h16x8 t[16];
    h16x8 hsum[2];
    #pragma unroll
    for (int h = 0; h < 2; ++h) {
        #pragma unroll
        for (int j = 0; j < 4; ++j) {
            int jj = h * 4 + j;
            int tl = rg * 8 + jj;
            int rv = sval[tl] * 7 + sdep[tl];
            t[j * 4 + 0] = *(const h16x8*)(vdw2 + (rv * 8 + jj) * 32 + q * 8);
            t[j * 4 + 1] = *(const h16x8*)(sew2 + ((size_t)(spos[tl * 3]      ) * 8 + jj) * 32 + q * 8);
            t[j * 4 + 2] = *(const h16x8*)(sew2 + ((size_t)(spos[tl * 3 + 1] + 128) * 8 + jj) * 32 + q * 8);
            t[j * 4 + 3] = *(const h16x8*)(sew2 + ((size_t)(spos[tl * 3 + 2] + 256) * 8 + jj) * 32 + q * 8);
        }
        h16x8 a0 = (t[0] + t[1]) + (t[2] + t[3]);
        h16x8 a1 = (t[4] + t[5]) + (t[6] + t[7]);
        h16x8 a2 = (t[8] + t[9]) + (t[10] + t[11]);
        h16x8 a3 = (t[12] + t[13]) + (t[14] + t[15]);
        hsum[h] = (a0 + a1) + (a2 + a3);
    }
    h16x8 s = hsum[0] + hsum[1];

    int d = dst2[b * L2P + l2b + rg];
    if (d >= 0) {
        float4 bb0 = *(const float4*)(b2 + q * 8);
        float4 bb1 = *(const float4*)(b2 + q * 8 + 4);
        h16x8 o8;
        o8[0] = (_Float16)((float)s[0] + bb0.x);
        o8[1] = (_Float16)((float)s[1] + bb0.y);
        o8[2] = (_Float16)((float)s[2] + bb0.z);
        o8[3] = (_Float16)((float)s[3] + bb0.w);
        o8[4] = (_Float16)((float)s[4] + bb1.x);
        o8[5] = (_Float16)((float)s[5] + bb1.y);
        o8[6] = (_Float16)((float)s[6] + bb1.z);
        o8[7] = (_Float16)((float)s[7] + bb1.w);
        *(h16x8*)(y_c + ((size_t)(b * L2P + d)) * CD + q * 8) = o8;
    }
}

// ---------------------------------------------------------------------------
// conv1 (MFMA f16, pipelined A and B): embed1 + substitution gather ->
// GEMM M=32768,K=256,N=256.  Block: 64M x 256N, 256 thr (4 waves 32Mx128N).
// Index loads COALESCED via LDS staging; sub tokens encoded as ~ord
// (all-zero table rows make the invalid-sub path collapse to zeros).
// ---------------------------------------------------------------------------
__global__ __launch_bounds__(256, 2) void k_conv1(
    const int* __restrict__ value, const int* __restrict__ depth,
    const int* __restrict__ pos,
    const _Float16* __restrict__ vd1h, const _Float16* __restrict__ se1h,
    const _Float16* __restrict__ w1h, const float* __restrict__ b1,
    const int* __restrict__ order1, const int* __restrict__ cnt2,
    const _Float16* __restrict__ y_c, float* __restrict__ out) {
    int tid = threadIdx.x, lane = tid & 63, wid = tid >> 6;
    int q = tid & 3, tg = tid >> 2;
    int g0 = blockIdx.x * 64, b = g0 >> 10, lb = g0 & (L1P - 1);
    __shared__ _Float16 As[2][64 * 64];    // 8 KB x2
    __shared__ _Float16 Bs[2][256 * 64];   // 32 KB x2
    f32x4 acc[2][8] = {};
    int m0 = (wid & 1) * 32, n0 = (wid >> 1) * 128;
    int c2 = cnt2[b];

    // ---- coalesced index staging into the As region (12 KB scratch) ----
    int* sval = (int*)&As[0][0];          // 512
    int* sord = sval + 512;               // 512
    int* sdep = sord + 512;               // 512
    int* spos = sdep + 512;               // 1536
    {
        int tok0 = b * LTOT + lb * 8;
        int o0 = b * L1N + lb * 8;
        const int4* vsrc = (const int4*)(value + tok0);
        const int4* dsrc = (const int4*)(depth + tok0);
        const int4* osrc = (const int4*)(order1 + o0);
        const int4* psrc = (const int4*)(pos + (size_t)tok0 * 3);
        if (tid < 128) { ((int4*)sval)[tid] = vsrc[tid]; ((int4*)sdep)[tid] = dsrc[tid]; }
        else { int o = tid - 128; ((int4*)sord)[o] = osrc[o]; ((int4*)spos)[o] = psrc[o]; }
        ((int4*)spos)[128 + tid] = psrc[128 + tid];    // 128..383
    }
    __syncthreads();
    int xv[8], p0v[8], p1v[8], p2v[8];
    #pragma unroll
    for (int j = 0; j < 8; ++j) {
        int t = (j & 1) * 64 + tg;
        int tl = (t >> 1) * 8 + (j >> 1) * 2 + (t & 1);
        int vv = sval[tl];
        if (vv == 2) {
            xv[j] = ~sord[tl];
            p0v[j] = 0; p1v[j] = 0; p2v[j] = 0;
        } else {
            xv[j] = (vv * 7 + sdep[tl]) * CD;
            p0v[j] = spos[tl * 3] * CD;
            p1v[j] = (spos[tl * 3 + 1] + 128) * CD;
            p2v[j] = (spos[tl * 3 + 2] + 256) * CD;
        }
    }
    __syncthreads();

    h16x8 row[2][4];
    h16x8 breg[8];
    #define PREF1(j, slot) { \
        int x_ = xv[j]; \
        h16x8 z = {}; \
        if (x_ < 0) { \
            int o_ = ~x_; \
            row[slot][0] = (o_ < c2) \
                ? *(const h16x8*)(y_c + ((size_t)(b * L2P + o_)) * CD + q * 8) : z; \
            row[slot][1] = z; row[slot][2] = z; row[slot][3] = z; \
        } else { \
            row[slot][0] = *(const h16x8*)(vd1h + x_ + q * 8); \
            row[slot][1] = *(const h16x8*)(se1h + p0v[j] + q * 8); \
            row[slot][2] = *(const h16x8*)(se1h + p1v[j] + q * 8); \
            row[slot][3] = *(const h16x8*)(se1h + p2v[j] + q * 8); \
        } }
    #define PACK1(j, slot, buf) { \
        int t_ = (j & 1) * 64 + tg, m_ = t_ >> 1, sh_ = t_ & 1; \
        h16x8 sum = (row[slot][0] + row[slot][1]) + \
                    (row[slot][2] + row[slot][3]); \
        int c16 = sh_ * 4 + q; \
        *(h16x8*)&As[buf][m_ * 64 + ((c16 ^ (m_ & 7)) * 8)] = sum; }
    #define BLOAD(kc) { \
        _Pragma("unroll") \
        for (int it = 0; it < 8; ++it) { \
            int idx = it * 256 + tid; \
            int o = idx >> 3, c16 = idx & 7; \
            breg[it] = *(const h16x8*)(w1h + o * 256 + (kc) * 64 + c16 * 8); } }
    #define BSTORE(buf) { \
        _Pragma("unroll") \
        for (int it = 0; it < 8; ++it) { \
            int idx = it * 256 + tid; \
            int o = idx >> 3, c16 = idx & 7; \
            *(h16x8*)&Bs[buf][o * 64 + ((c16 ^ (o & 7)) * 8)] = breg[it]; } }

    BLOAD(0); PREF1(0, 0); PREF1(1, 1);
    BSTORE(0); PACK1(0, 0, 0); PACK1(1, 1, 0);
    __syncthreads();

    #pragma unroll
    for (int kc = 0; kc < 4; ++kc) {
        int cur = kc & 1;
        if (kc < 3) { BLOAD(kc + 1); PREF1(2 * kc + 2, 0); PREF1(2 * kc + 3, 1); }
        // ---- MFMA: 2 m-frags x 8 n-frags x 2 K-steps ----
        #pragma unroll
        for (int ks = 0; ks < 2; ++ks) {
            int c16 = ks * 4 + (lane >> 4);
            int r0 = m0 + (lane & 15), r1 = r0 + 16;
            h16x8 a0 = *(const h16x8*)&As[cur][r0 * 64 + ((c16 ^ (r0 & 7)) * 8)];
            h16x8 a1 = *(const h16x8*)&As[cur][r1 * 64 + ((c16 ^ (r1 & 7)) * 8)];
            #pragma unroll
            for (int nt = 0; nt < 8; ++nt) {
                int n = n0 + nt * 16 + (lane & 15);
                h16x8 bv = *(const h16x8*)&Bs[cur][n * 64 + ((c16 ^ (n & 7)) * 8)];
                acc[0][nt] = __builtin_amdgcn_mfma_f32_16x16x32_f16(a0, bv, acc[0][nt], 0, 0, 0);
                acc[1][nt] = __builtin_amdgcn_mfma_f32_16x16x32_f16(a1, bv, acc[1][nt], 0, 0, 0);
            }
        }
        if (kc < 3) {
            BSTORE(cur ^ 1);
            PACK1(2 * kc + 2, 0, cur ^ 1); PACK1(2 * kc + 3, 1, cur ^ 1);
        }
        __syncthreads();
    }

    // ---- epilogue: bias + fp32 store ----
    #pragma unroll
    for (int nt = 0; nt < 8; ++nt) {
        int n = n0 + nt * 16 + (lane & 15);
        float bias = b1[n];
        #pragma unroll
        for (int mt = 0; mt < 2; ++mt)
            #pragma unroll
            for (int r = 0; r < 4; ++r) {
                int g = g0 + m0 + mt * 16 + (lane >> 4) * 4 + r;
                out[(size_t)g * O1 + n] = acc[mt][nt][r] + bias;
            }
    }
    #undef PREF1
    #undef PACK1
    #undef BLOAD
    #undef BSTORE
}

// ---------------------------------------------------------------------------
extern "C" void kernel_launch(void* const* d_in, const int* in_sizes, int n_in,
                              void* d_out, int out_size, void* d_ws, size_t ws_size,
                              hipStream_t stream) {
    const int* value = (const int*)d_in[0];
    const int* depth = (const int*)d_in[1];
    const int* pos   = (const int*)d_in[2];
    const float* ve1 = (const float*)d_in[5];
    const float* de1 = (const float*)d_in[6];
    const float* se1 = (const float*)d_in[7];
    const float* ve2 = (const float*)d_in[8];
    const float* de2 = (const float*)d_in[9];
    const float* se2 = (const float*)d_in[10];
    const float* w1  = (const float*)d_in[11];
    const float* b1  = (const float*)d_in[12];
    const float* w2  = (const float*)d_in[13];
    const float* b2  = (const float*)d_in[14];
    float* out = (float*)d_out;

    char* ws = (char*)d_ws;
    _Float16* w1h  = (_Float16*)(ws);                         // 128 KB
    _Float16* vd1h = (_Float16*)(ws + 131072);                // 8 KB slot
    _Float16* se1h = (_Float16*)(ws + 139264);                // 24 KB
    _Float16* vdw2 = (_Float16*)(ws + 163840);                // 64 KB slot (61 KB used)
    _Float16* sew2 = (_Float16*)(ws + 229376);                // 192 KB (196608 B)
    _Float16* y_c  = (_Float16*)(ws + 425984);                // 8 MB
    int* order1 = (int*)(ws + 425984 + 8388608);              // 1 MB
    int* dst2   = (int*)(ws + 425984 + 8388608 + 1048576);    // 512 KB
    int* cnt2   = (int*)(ws + 425984 + 8388608 + 1048576 + 524288); // 128 B

    k_prescan<<<320, 256, 0, stream>>>(value, w1, w2, ve1, de1, se1,
                                       ve2, de2, se2, w1h, vd1h, se1h,
                                       vdw2, sew2, order1, dst2, cnt2);
    k_conv2<<<2048, 256, 0, stream>>>(value, depth, pos, vdw2, sew2,
                                      b2, dst2, y_c);
    k_conv1<<<512, 256, 0, stream>>>(value, depth, pos, vd1h, se1h,
                                     w1h, b1, order1, cnt2, y_c, out);
}